// Round 12
// baseline (113.368 us; speedup 1.0000x reference)
//
#include <hip/hip_runtime.h>
#include <hip/hip_bf16.h>
#include <cstdint>

#define HIDDEN 384
#define NSUPER 2048
#define FRAGS (12*24*64)
#define WBLK  (FRAGS*8)             // shorts per repacked 384x384 block = 147456
#define EGSLOTS 3072                // 48 frags x 64 lanes per 64-edge block

typedef __attribute__((ext_vector_type(8))) short bf16x8;
typedef __attribute__((ext_vector_type(4))) float f32x4;

// branchless RNE f32->bf16 (finite values only)
__device__ inline unsigned short f2bf(float f) {
    unsigned int u = __float_as_uint(f);
    return (unsigned short)((u + 0x7fffu + ((u >> 16) & 1u)) >> 16);
}
__device__ inline bf16x8 pack8(const float* v) {
    union { bf16x8 v8; unsigned short u[8]; } u;
    #pragma unroll
    for (int i = 0; i < 8; ++i) u.u[i] = f2bf(v[i]);
    return u.v8;
}
// tanh-form gelu via sigmoid: ~9 VALU ops, |err| <= ~1e-3 on gelu
__device__ inline float gelu(float y) {
    const float y2 = y * y;
    const float m  = __expf(y * fmaf(-0.0713548163f, y2, -1.5957691216f));
    return y * (1.0f / (1.0f + m));
}

// ---- K1: repacks + W2@Wp_top product + c2p + mask detect + sn embeds ----
// b in [0,216): repack {W1 top, W1 bot, Wp bot}; [216,288): W2p; 288: mask;
// 289: c2p = b2 @ Wp_top; [290,322): supernode embeds.
__global__ __launch_bounds__(256)
void prep(const float* __restrict__ W1, const float* __restrict__ W2,
          const float* __restrict__ Wp, const float* __restrict__ b2,
          const unsigned int* __restrict__ mask,
          const float* __restrict__ pos, const float* __restrict__ feat,
          const int* __restrict__ sn_idx,
          const float* __restrict__ W_in, const float* __restrict__ b_in,
          unsigned short* __restrict__ w1sf, unsigned short* __restrict__ w1df,
          unsigned short* __restrict__ w2pf, unsigned short* __restrict__ wpbf,
          float* __restrict__ c2p,
          unsigned short* __restrict__ snxb, int* __restrict__ flag) {
    const int b = blockIdx.x;
    const int t = threadIdx.x;
    if (b == 288) {   // mask detect: uint8 numpy-bool vs int32
        __shared__ int s;
        if (t == 0) s = 0;
        __syncthreads();
        int bad = 0;
        for (int i = t; i < 16384; i += 256)
            if (mask[i] > 1u) bad = 1;
        if (bad) s = 1;
        __syncthreads();
        if (t == 0) *flag = s;
        return;
    }
    if (b == 289) {   // c2p[col] = sum_k b2[k] * Wp[k][col]  (top half of Wp)
        for (int col = t; col < HIDDEN; col += 256) {
            float s = 0.f;
            for (int k = 0; k < HIDDEN; ++k)
                s += b2[k] * Wp[(size_t)k*HIDDEN + col];
            c2p[col] = s;
        }
        return;
    }
    if (b >= 290) {   // ---- supernode embeds -> snxb ----
        __shared__ float W4[HIDDEN][4];
        __shared__ float P6[64][7];
        const int eb = b - 290;   // 0..31
        if (t < 64) {
            const int pi = sn_idx[eb*64 + t];
            P6[t][0]=pos[pi*3];  P6[t][1]=pos[pi*3+1];  P6[t][2]=pos[pi*3+2];
            P6[t][3]=feat[pi*3]; P6[t][4]=feat[pi*3+1]; P6[t][5]=feat[pi*3+2];
        }
        for (int d = t; d < HIDDEN; d += 256) {
            W4[d][0]=W_in[d]; W4[d][1]=W_in[HIDDEN+d];
            W4[d][2]=W_in[2*HIDDEN+d]; W4[d][3]=b_in[d];
        }
        __syncthreads();
        const int er = t >> 2, seg = t & 3;
        float frA[8], frB[8];
        #pragma unroll
        for (int i = 0; i < 8; ++i) {
            frA[i] = exp2f(-(float)(seg*8 + i)      * 0.2076205059304601f);
            frB[i] = exp2f(-(float)(32 + seg*8 + i) * 0.2076205059304601f);
        }
        const float f0 = P6[er][3], f1 = P6[er][4], f2 = P6[er][5];
        #pragma unroll
        for (int cc = 0; cc < 3; ++cc) {
            const float pc = P6[er][cc];
            float sL[8], sH[8], cL[8], cH[8];
            #pragma unroll
            for (int i = 0; i < 8; ++i) {
                const float aL = pc*frA[i], aH = pc*frB[i];
                sL[i]=__sinf(aL); sH[i]=__sinf(aH); cL[i]=__cosf(aL); cH[i]=__cosf(aH);
            }
            #pragma unroll
            for (int q = 0; q < 4; ++q) {
                const float* bb = (q==0)?sL:(q==1)?sH:(q==2)?cL:cH;
                const int blk = cc*4 + q;
                float v[8];
                #pragma unroll
                for (int i = 0; i < 8; ++i) {
                    const int dim = blk*32 + seg*8 + i;
                    const float4 wv = *(const float4*)W4[dim];
                    v[i] = fmaf(f0, wv.x, fmaf(f1, wv.y, fmaf(f2, wv.z, bb[i] + wv.w)));
                }
                *(bf16x8*)&snxb[(size_t)(eb*64 + er)*HIDDEN + blk*32 + seg*8] = pack8(v);
            }
        }
        return;
    }
    if (b >= 216) {   // ---- W2p = W2 @ Wp_top, fp32 accum, frag-major bf16 out ----
        const int idx = (b - 216)*256 + t;   // 0..18431 = (frag, lane)
        const int l = idx & 63, frag = idx >> 6;
        const int nt = frag % 24, kt = frag / 24;
        const int col = nt*16 + (l & 15);
        const int r0  = kt*32 + (l >> 4)*8;
        float a8[8];
        #pragma unroll
        for (int j = 0; j < 8; ++j) a8[j] = 0.f;
        for (int k = 0; k < HIDDEN; k += 4) {
            const float wp0 = Wp[(size_t)(k+0)*HIDDEN + col];
            const float wp1 = Wp[(size_t)(k+1)*HIDDEN + col];
            const float wp2 = Wp[(size_t)(k+2)*HIDDEN + col];
            const float wp3 = Wp[(size_t)(k+3)*HIDDEN + col];
            #pragma unroll
            for (int j = 0; j < 8; ++j) {
                const float4 w2v = *(const float4*)&W2[(size_t)(r0+j)*HIDDEN + k];
                a8[j] += w2v.x*wp0 + w2v.y*wp1 + w2v.z*wp2 + w2v.w*wp3;
            }
        }
        unsigned int pk[4];
        #pragma unroll
        for (int j = 0; j < 4; ++j)
            pk[j] = (unsigned int)f2bf(a8[2*j]) | ((unsigned int)f2bf(a8[2*j+1]) << 16);
        *reinterpret_cast<uint4*>(&w2pf[(size_t)idx*8]) =
            *reinterpret_cast<const uint4*>(pk);
        return;
    }
    // ---- repack (3 groups x 72 blocks) ----
    const int grp = b / 72, sub = b % 72;
    const float* W; unsigned short* out;
    switch (grp) {
        case 0: W = W1;              out = w1sf; break;
        case 1: W = W1 + 384*HIDDEN; out = w1df; break;
        default:W = Wp + 384*HIDDEN; out = wpbf; break;
    }
    const int idx = sub * 256 + t;
    const int l   = idx & 63;
    const int frag= idx >> 6;
    const int nt  = frag % 24;
    const int kt  = frag / 24;
    const int col = nt * 16 + (l & 15);
    const int k0  = kt * 32 + (l >> 4) * 8;
    unsigned int pk[4];
    #pragma unroll
    for (int j = 0; j < 4; ++j) {
        unsigned int lo = f2bf(W[(size_t)(k0 + 2*j)     * HIDDEN + col]);
        unsigned int hi = f2bf(W[(size_t)(k0 + 2*j + 1) * HIDDEN + col]);
        pk[j] = lo | (hi << 16);
    }
    *reinterpret_cast<uint4*>(&out[(size_t)idx * 8]) =
        *reinterpret_cast<const uint4*>(pk);
}

// ---- K2: edge embeds -> eG (frag-major bf16, chunk-local). High occupancy:
// tiny LDS, no MFMA; the trig VALU is no longer hostage to GEMM residency.
__global__ __launch_bounds__(256)
void k_emb(const float* __restrict__ pos, const float* __restrict__ feat,
           const int* __restrict__ nbr_idx,
           const float* __restrict__ W_in, const float* __restrict__ b_in,
           unsigned short* __restrict__ eG, int cbase)
{
    __shared__ float PF[64][6];
    __shared__ float W4[HIDDEN][4];
    const int t = threadIdx.x;
    const int bmL = blockIdx.x, bmG = cbase + bmL;
    if (t < 64) {
        const int pi = nbr_idx[bmG*64 + t];
        PF[t][0]=pos[pi*3];  PF[t][1]=pos[pi*3+1];  PF[t][2]=pos[pi*3+2];
        PF[t][3]=feat[pi*3]; PF[t][4]=feat[pi*3+1]; PF[t][5]=feat[pi*3+2];
    }
    for (int d = t; d < HIDDEN; d += 256) {
        W4[d][0]=W_in[d]; W4[d][1]=W_in[HIDDEN+d];
        W4[d][2]=W_in[2*HIDDEN+d]; W4[d][3]=b_in[d];
    }
    __syncthreads();
    const int er = t >> 2, seg = t & 3;
    float frA[8], frB[8];
    #pragma unroll
    for (int i = 0; i < 8; ++i) {
        frA[i] = exp2f(-(float)(seg*8 + i)      * 0.2076205059304601f);
        frB[i] = exp2f(-(float)(32 + seg*8 + i) * 0.2076205059304601f);
    }
    const float f0 = PF[er][3], f1 = PF[er][4], f2 = PF[er][5];
    const int slotb = (er>>4)*768 + seg*16 + (er&15);
    unsigned short* dst = &eG[(size_t)bmL * EGSLOTS * 8];
    #pragma unroll
    for (int cc = 0; cc < 3; ++cc) {
        const float pc = PF[er][cc];
        float sL[8], sH[8], cL[8], cH[8];
        #pragma unroll
        for (int i = 0; i < 8; ++i) {
            const float aL = pc*frA[i], aH = pc*frB[i];
            sL[i]=__sinf(aL); sH[i]=__sinf(aH); cL[i]=__cosf(aL); cH[i]=__cosf(aH);
        }
        #pragma unroll
        for (int q = 0; q < 4; ++q) {
            const float* bb = (q==0)?sL:(q==1)?sH:(q==2)?cL:cH;
            const int blk = cc*4 + q;   // = kt; frag slot = (er>>4)*12 + blk
            float v[8];
            #pragma unroll
            for (int i = 0; i < 8; ++i) {
                const int dim = blk*32 + seg*8 + i;
                const float4 wv = *(const float4*)W4[dim];
                v[i] = fmaf(f0, wv.x, fmaf(f1, wv.y, fmaf(f2, wv.z, bb[i] + wv.w)));
            }
            *(bf16x8*)&dst[(size_t)(slotb + blk*64)*8] = pack8(v);
        }
    }
}

// ---- K3: pure-GEMM edge MLP layer 1 + gelu + masked mean -> aggpre ----
// Phase A: dst bcast MFMA (A from snxb through L1, no LDS). Phase B: src MFMA
// with A-fragments loaded DIRECTLY from eG into registers (frag-major layout
// == MFMA register layout; each fragment read exactly once). No G in LDS, no
// barriers in the GEMM, ~0 bank conflicts.
__global__ __launch_bounds__(256, 2)
void k_mlp(const int* __restrict__ nbr_idx, const void* __restrict__ mask_raw,
           const int* __restrict__ mask_fmt,
           const unsigned short* __restrict__ snxb,
           const unsigned short* __restrict__ W1sf,
           const unsigned short* __restrict__ W1df,
           const unsigned short* __restrict__ eG,
           const float* __restrict__ b1,
           unsigned short* __restrict__ aggpre, float* __restrict__ cntf,
           int cbase)
{
    __shared__ float MV[64];
    __shared__ float CNT[2];
    const int t = threadIdx.x;
    const int bmL = blockIdx.x, bmG = cbase + bmL;
    const int l = t & 63, ng = t >> 6, lg = l >> 4, l15 = l & 15;

    if (t < 64) {
        const int e = bmG*64 + t;
        const int fmt = *mask_fmt;
        const int mv = fmt ? (int)((const unsigned char*)mask_raw)[e]
                           : ((const int*)mask_raw)[e];
        MV[t] = mv ? 1.0f : 0.0f;
    }
    __syncthreads();
    if (t < 2) {
        float c = 0.f;
        for (int s = 0; s < 32; ++s) c += MV[t*32+s];
        CNT[t] = c;
    }
    __syncthreads();

    float b1r[6];
    #pragma unroll
    for (int nt = 0; nt < 6; ++nt) b1r[nt] = b1[ng*96 + nt*16 + l15];

    bf16x8 bA[6], bB[6];
    #define LOADB(dst, Wf, kt)                                                  \
        { const unsigned short* bp_ = &Wf[((size_t)((kt)*24 + ng*6)*64 + l)*8]; \
          _Pragma("unroll")                                                     \
          for (int nt_ = 0; nt_ < 6; ++nt_)                                     \
              dst[nt_] = *(const bf16x8*)(bp_ + (size_t)nt_*512); }
    #define ALOAD(a_, kt)                                                       \
        { _Pragma("unroll")                                                     \
          for (int mt_ = 0; mt_ < 4; ++mt_)                                     \
              a_[mt_] = *(const bf16x8*)&eGb[(size_t)(((mt_*12 + (kt))*64) + l)*8]; }
    #define MFMA6(bfr, a_)                                                      \
        { __builtin_amdgcn_s_setprio(1);                                        \
          _Pragma("unroll")                                                     \
          for (int mt_ = 0; mt_ < 4; ++mt_)                                     \
              _Pragma("unroll")                                                 \
              for (int nt_ = 0; nt_ < 6; ++nt_)                                 \
                  acc[mt_][nt_] = __builtin_amdgcn_mfma_f32_16x16x32_bf16(      \
                      a_[mt_], bfr[nt_], acc[mt_][nt_], 0, 0, 0);               \
          __builtin_amdgcn_s_setprio(0); }

    f32x4 acc[4][6];
    #pragma unroll
    for (int mt=0; mt<4; ++mt)
        #pragma unroll
        for (int nt=0; nt<6; ++nt) acc[mt][nt] = (f32x4){0.f,0.f,0.f,0.f};

    const unsigned short* eGb = &eG[(size_t)bmL * EGSLOTS * 8];

    // ---- phase A: dst-half GEMM (snxb broadcast A); eG kt=0,1 prefetched
    // so their HBM/L3 latency hides under 12 iterations of MFMA ----
    bf16x8 aX[4], aY[4];
    ALOAD(aX, 0);
    ALOAD(aY, 1);
    const unsigned short* snx0 = &snxb[(size_t)(bmG*2 + 0)*HIDDEN];
    const unsigned short* snx1 = &snxb[(size_t)(bmG*2 + 1)*HIDDEN];
    #pragma unroll
    for (int kt = 0; kt < 12; ++kt) {
        LOADB(bA, W1df, kt);
        bf16x8 s0 = *(const bf16x8*)&snx0[kt*32 + lg*8];
        bf16x8 s1 = *(const bf16x8*)&snx1[kt*32 + lg*8];
        __builtin_amdgcn_s_setprio(1);
        #pragma unroll
        for (int nt = 0; nt < 6; ++nt) {
            acc[0][nt] = __builtin_amdgcn_mfma_f32_16x16x32_bf16(s0, bA[nt], acc[0][nt], 0,0,0);
            acc[1][nt] = __builtin_amdgcn_mfma_f32_16x16x32_bf16(s0, bA[nt], acc[1][nt], 0,0,0);
            acc[2][nt] = __builtin_amdgcn_mfma_f32_16x16x32_bf16(s1, bA[nt], acc[2][nt], 0,0,0);
            acc[3][nt] = __builtin_amdgcn_mfma_f32_16x16x32_bf16(s1, bA[nt], acc[3][nt], 0,0,0);
        }
        __builtin_amdgcn_s_setprio(0);
    }

    // ---- phase B: src-half GEMM, A direct-from-global, 2-deep dbuf ----
    LOADB(bA, W1sf, 0);
    LOADB(bB, W1sf, 1);
    #pragma unroll
    for (int kt = 0; kt < 12; kt += 2) {
        MFMA6(bA, aX);
        if (kt + 2 < 12) { ALOAD(aX, kt + 2); LOADB(bA, W1sf, kt + 2); }
        MFMA6(bB, aY);
        if (kt + 3 < 12) { ALOAD(aY, kt + 3); LOADB(bB, W1sf, kt + 3); }
    }

    // ---- gelu + masked mean -> aggpre ----
    float mvr[4][4];
    #pragma unroll
    for (int mt=0; mt<4; ++mt)
        #pragma unroll
        for (int r=0; r<4; ++r)
            mvr[mt][r] = MV[mt*16 + lg*4 + r];
    #pragma unroll
    for (int nt=0; nt<6; ++nt) {
        const int col = ng*96 + nt*16 + l15;
        const float bb1 = b1r[nt];
        float s0 = 0.f, s1 = 0.f;
        #pragma unroll
        for (int mt=0; mt<4; ++mt) {
            float p = 0.f;
            #pragma unroll
            for (int r=0; r<4; ++r)
                p += mvr[mt][r] * gelu(acc[mt][nt][r] + bb1);
            if (mt < 2) s0 += p; else s1 += p;
        }
        s0 += __shfl_xor(s0,16); s0 += __shfl_xor(s0,32);
        s1 += __shfl_xor(s1,16); s1 += __shfl_xor(s1,32);
        if (lg == 0) {
            const int sn0 = bmG*2;
            aggpre[(size_t)sn0*HIDDEN + col]     = f2bf(s0 / fmaxf(CNT[0],1.f));
            aggpre[(size_t)(sn0+1)*HIDDEN + col] = f2bf(s1 / fmaxf(CNT[1],1.f));
        }
    }
    if (t < 2) cntf[bmG*2 + t] = CNT[t];
    #undef LOADB
    #undef ALOAD
    #undef MFMA6
}

// ---- K4: merged agg+proj: out = aggpre@W2p + snxb@Wp_bot + bp + nz*c2p ----
__global__ __launch_bounds__(256)
void k_proj(const unsigned short* __restrict__ aggp,
            const unsigned short* __restrict__ snxb,
            const unsigned short* __restrict__ w2pf,
            const unsigned short* __restrict__ wpbf,
            const float* __restrict__ bp, const float* __restrict__ c2p,
            const float* __restrict__ cntf, float* __restrict__ out) {
    const int rg = blockIdx.x >> 2, cq = blockIdx.x & 3;
    const int t = threadIdx.x, w = t>>6, l = t&63, lg = l>>4, l15 = l&15;
    const int wgm = w>>1, wgn = w&1;
    const int r0 = rg*64 + wgm*32;
    const int ntb = cq*6 + wgn*3;
    f32x4 acc[2][3];
    #pragma unroll
    for (int mt=0; mt<2; ++mt)
        #pragma unroll
        for (int nt=0; nt<3; ++nt) acc[mt][nt] = (f32x4){0.f,0.f,0.f,0.f};
    #pragma unroll 2
    for (int kt = 0; kt < 24; ++kt) {
        const unsigned short* Ab = (kt < 12) ? aggp : snxb;
        const unsigned short* Wb = (kt < 12) ? w2pf : wpbf;
        const int ktt = (kt < 12) ? kt : kt - 12;
        bf16x8 a[2], bfr[3];
        const unsigned short* bpp = &Wb[((size_t)(ktt*24 + ntb)*64 + l)*8];
        #pragma unroll
        for (int nt=0; nt<3; ++nt) bfr[nt] = *(const bf16x8*)(bpp + (size_t)nt*512);
        #pragma unroll
        for (int mt=0; mt<2; ++mt)
            a[mt] = *(const bf16x8*)&Ab[(size_t)(r0 + mt*16 + l15)*HIDDEN + ktt*32 + lg*8];
        #pragma unroll
        for (int mt=0; mt<2; ++mt)
            #pragma unroll
            for (int nt=0; nt<3; ++nt)
                acc[mt][nt] = __builtin_amdgcn_mfma_f32_16x16x32_bf16(a[mt], bfr[nt], acc[mt][nt], 0,0,0);
    }
    #pragma unroll
    for (int mt=0; mt<2; ++mt)
        #pragma unroll
        for (int nt=0; nt<3; ++nt) {
            const int col = cq*96 + wgn*48 + nt*16 + l15;
            const float bbp = bp[col];
            const float cc2 = c2p[col];
            #pragma unroll
            for (int r=0; r<4; ++r) {
                const int row = r0 + mt*16 + lg*4 + r;
                const float nz = (cntf[row] > 0.f) ? 1.f : 0.f;
                out[(size_t)row*HIDDEN + col] = acc[mt][nt][r] + bbp + nz*cc2;
            }
        }
}

extern "C" void kernel_launch(void* const* d_in, const int* in_sizes, int n_in,
                              void* d_out, int out_size, void* d_ws, size_t ws_size,
                              hipStream_t stream) {
    const float* pos   = (const float*)d_in[0];
    const float* feat  = (const float*)d_in[1];
    const int*   sn    = (const int*)d_in[2];
    const int*   nbr   = (const int*)d_in[3];
    const void*  mask  = d_in[4];
    const float* W_in  = (const float*)d_in[5];
    const float* b_in  = (const float*)d_in[6];
    const float* W1    = (const float*)d_in[7];
    const float* b1    = (const float*)d_in[8];
    const float* W2    = (const float*)d_in[9];
    const float* b2    = (const float*)d_in[10];
    const float* Wp    = (const float*)d_in[11];
    const float* bpv   = (const float*)d_in[12];
    float* out = (float*)d_out;

    char* base = (char*)d_ws;
    int*   flag = (int*)base;
    float* c2p  = (float*)(base + 256);
    unsigned short* w1sf = (unsigned short*)(base + 2048);
    unsigned short* w1df = w1sf + WBLK;
    unsigned short* w2pf = w1df + WBLK;
    unsigned short* wpbf = w2pf + WBLK;
    unsigned short* snxb = wpbf + WBLK;                   // 2048*384 bf16
    unsigned short* aggp = snxb + (size_t)NSUPER*HIDDEN;  // 2048*384 bf16
    float* cntf = (float*)(aggp + (size_t)NSUPER*HIDDEN); // 2048 f32
    unsigned short* eG = (unsigned short*)((char*)cntf + NSUPER*sizeof(float));
    const size_t base_need = (size_t)((char*)eG - base);  // 4,335,616 B
    const size_t EG_BYTES = (size_t)65536 * HIDDEN * 2;   // 48 MB full

    // chunk count: smallest C with base + eG/C fitting in ws (deterministic)
    int C = 1;
    while (C < 16 && base_need + EG_BYTES / (size_t)C > ws_size) C <<= 1;
    const int bpc = 1024 / C;

    hipLaunchKernelGGL(prep, dim3(322), dim3(256), 0, stream,
                       W1, W2, Wp, b2, (const unsigned int*)mask,
                       pos, feat, sn, W_in, b_in,
                       w1sf, w1df, w2pf, wpbf, c2p, snxb, flag);
    for (int c = 0; c < C; ++c) {
        hipLaunchKernelGGL(k_emb, dim3(bpc), dim3(256), 0, stream,
                           pos, feat, nbr, W_in, b_in, eG, c*bpc);
        hipLaunchKernelGGL(k_mlp, dim3(bpc), dim3(256), 0, stream,
                           nbr, mask, flag, snxb, w1sf, w1df, eG, b1,
                           aggp, cntf, c*bpc);
    }
    hipLaunchKernelGGL(k_proj, dim3(128), dim3(256), 0, stream,
                       aggp, snxb, w2pf, wpbf, bpv, c2p, cntf, out);
}

// Round 13
// 87.213 us; speedup vs baseline: 1.2999x; 1.2999x over previous
//
#include <hip/hip_runtime.h>
#include <hip/hip_bf16.h>
#include <cstdint>

#define HIDDEN 384
#define NSUPER 2048
#define FRAGS (12*24*64)
#define WBLK  (FRAGS*8)             // shorts per repacked 384x384 block = 147456

typedef __attribute__((ext_vector_type(8))) short bf16x8;
typedef __attribute__((ext_vector_type(4))) float f32x4;

// branchless RNE f32->bf16 (finite values only)
__device__ inline unsigned short f2bf(float f) {
    unsigned int u = __float_as_uint(f);
    return (unsigned short)((u + 0x7fffu + ((u >> 16) & 1u)) >> 16);
}
__device__ inline bf16x8 pack8(const float* v) {
    union { bf16x8 v8; unsigned short u[8]; } u;
    #pragma unroll
    for (int i = 0; i < 8; ++i) u.u[i] = f2bf(v[i]);
    return u.v8;
}
// tanh-form gelu via sigmoid: ~9 VALU ops, |err| <= ~1e-3 on gelu
__device__ inline float gelu(float y) {
    const float y2 = y * y;
    const float m  = __expf(y * fmaf(-0.0713548163f, y2, -1.5957691216f));
    return y * (1.0f / (1.0f + m));
}

// ---- K1: weight repacks + mask detect + supernode embeds (r11 version) ----
__global__ __launch_bounds__(256)
void prep(const float* __restrict__ W1, const float* __restrict__ W2,
          const float* __restrict__ Wp, const unsigned int* __restrict__ mask,
          const float* __restrict__ pos, const float* __restrict__ feat,
          const int* __restrict__ sn_idx,
          const float* __restrict__ W_in, const float* __restrict__ b_in,
          unsigned short* __restrict__ w1sf, unsigned short* __restrict__ w1df,
          unsigned short* __restrict__ w2f,  unsigned short* __restrict__ wpf,
          unsigned short* __restrict__ snxb, int* __restrict__ flag) {
    const int b = blockIdx.x;
    const int t = threadIdx.x;
    if (b == 360) {   // mask detect: uint8 numpy-bool vs int32
        __shared__ int s;
        if (t == 0) s = 0;
        __syncthreads();
        int bad = 0;
        for (int i = t; i < 16384; i += 256)
            if (mask[i] > 1u) bad = 1;
        if (bad) s = 1;
        __syncthreads();
        if (t == 0) *flag = s;   // 1 => uint8, 0 => int32
        return;
    }
    if (b > 360) {    // ---- supernode embeds -> snxb ----
        __shared__ float W4[HIDDEN][4];
        __shared__ float P6[64][7];
        const int eb = b - 361;   // 0..31
        if (t < 64) {
            const int pi = sn_idx[eb*64 + t];
            P6[t][0]=pos[pi*3];  P6[t][1]=pos[pi*3+1];  P6[t][2]=pos[pi*3+2];
            P6[t][3]=feat[pi*3]; P6[t][4]=feat[pi*3+1]; P6[t][5]=feat[pi*3+2];
        }
        for (int d = t; d < HIDDEN; d += 256) {
            W4[d][0]=W_in[d]; W4[d][1]=W_in[HIDDEN+d];
            W4[d][2]=W_in[2*HIDDEN+d]; W4[d][3]=b_in[d];
        }
        __syncthreads();
        const int er = t >> 2, seg = t & 3;
        float frA[8], frB[8];
        #pragma unroll
        for (int i = 0; i < 8; ++i) {
            frA[i] = exp2f(-(float)(seg*8 + i)      * 0.2076205059304601f);
            frB[i] = exp2f(-(float)(32 + seg*8 + i) * 0.2076205059304601f);
        }
        const float f0 = P6[er][3], f1 = P6[er][4], f2 = P6[er][5];
        #pragma unroll
        for (int cc = 0; cc < 3; ++cc) {
            const float pc = P6[er][cc];
            float sL[8], sH[8], cL[8], cH[8];
            #pragma unroll
            for (int i = 0; i < 8; ++i) {
                const float aL = pc*frA[i], aH = pc*frB[i];
                sL[i]=__sinf(aL); sH[i]=__sinf(aH); cL[i]=__cosf(aL); cH[i]=__cosf(aH);
            }
            #pragma unroll
            for (int q = 0; q < 4; ++q) {
                const float* bb = (q==0)?sL:(q==1)?sH:(q==2)?cL:cH;
                const int blk = cc*4 + q;
                float v[8];
                #pragma unroll
                for (int i = 0; i < 8; ++i) {
                    const int dim = blk*32 + seg*8 + i;
                    const float4 wv = *(const float4*)W4[dim];
                    v[i] = fmaf(f0, wv.x, fmaf(f1, wv.y, fmaf(f2, wv.z, bb[i] + wv.w)));
                }
                *(bf16x8*)&snxb[(size_t)(eb*64 + er)*HIDDEN + blk*32 + seg*8] = pack8(v);
            }
        }
        return;
    }
    // ---- repack: frag (kt,nt): lane l elem j = W[kt*32+(l>>4)*8+j][nt*16+(l&15)]
    const int grp = b / 72, sub = b % 72;
    const float* W; unsigned short* out;
    switch (grp) {
        case 0: W = W1;              out = w1sf; break;
        case 1: W = W1 + 384*HIDDEN; out = w1df; break;
        case 2: W = W2;              out = w2f;  break;
        case 3: W = Wp;              out = wpf;  break;
        default:W = Wp + 384*HIDDEN; out = wpf + WBLK; break;
    }
    const int idx = sub * 256 + t;   // 72*256 == FRAGS exactly
    const int l   = idx & 63;
    const int frag= idx >> 6;
    const int nt  = frag % 24;
    const int kt  = frag / 24;
    const int col = nt * 16 + (l & 15);
    const int k0  = kt * 32 + (l >> 4) * 8;
    unsigned int pk[4];
    #pragma unroll
    for (int j = 0; j < 4; ++j) {
        unsigned int lo = f2bf(W[(size_t)(k0 + 2*j)     * HIDDEN + col]);
        unsigned int hi = f2bf(W[(size_t)(k0 + 2*j + 1) * HIDDEN + col]);
        pk[j] = lo | (hi << 16);
    }
    *reinterpret_cast<uint4*>(&out[(size_t)idx * 8]) =
        *reinterpret_cast<const uint4*>(pk);
}

// ---- K2: dstv[2048][384] = snxb @ W1dst + b1 (r8 version, ~5us) ----
__global__ __launch_bounds__(256)
void k_dstv(const unsigned short* __restrict__ snxb,
            const unsigned short* __restrict__ w1df,
            const float* __restrict__ b1, float* __restrict__ dstv) {
    const int rg = blockIdx.x >> 2, cq = blockIdx.x & 3;
    const int t = threadIdx.x, w = t>>6, l = t&63, lg = l>>4, l15 = l&15;
    const int wgm = w>>1, wgn = w&1;
    const int r0 = rg*64 + wgm*32;
    const int ntb = cq*6 + wgn*3;
    f32x4 acc[2][3];
    #pragma unroll
    for (int mt=0; mt<2; ++mt)
        #pragma unroll
        for (int nt=0; nt<3; ++nt) acc[mt][nt] = (f32x4){0.f,0.f,0.f,0.f};
    #pragma unroll 2
    for (int kt = 0; kt < 12; ++kt) {
        bf16x8 a[2], bfr[3];
        const unsigned short* bpp = &w1df[((size_t)(kt*24 + ntb)*64 + l)*8];
        #pragma unroll
        for (int nt=0; nt<3; ++nt) bfr[nt] = *(const bf16x8*)(bpp + (size_t)nt*512);
        #pragma unroll
        for (int mt=0; mt<2; ++mt)
            a[mt] = *(const bf16x8*)&snxb[(size_t)(r0 + mt*16 + l15)*HIDDEN + kt*32 + lg*8];
        #pragma unroll
        for (int mt=0; mt<2; ++mt)
            #pragma unroll
            for (int nt=0; nt<3; ++nt)
                acc[mt][nt] = __builtin_amdgcn_mfma_f32_16x16x32_bf16(a[mt], bfr[nt], acc[mt][nt], 0,0,0);
    }
    #pragma unroll
    for (int mt=0; mt<2; ++mt)
        #pragma unroll
        for (int nt=0; nt<3; ++nt) {
            const int col = cq*96 + wgn*48 + nt*16 + l15;
            #pragma unroll
            for (int r=0; r<4; ++r) {
                const int row = r0 + mt*16 + lg*4 + r;
                dstv[(size_t)row*HIDDEN + col] = acc[mt][nt][r] + b1[col];
            }
        }
}

// ---- K3: fused edge MLP, BM=128 (4 supernodes), 512 thr = 8 waves ----
// Only W1src streams per block (dst term precomputed in k_dstv). mg-wave
// pairs (mg=0,1; same ng) read identical B fragments in near-lockstep on
// the same CU -> L1 reuse halves the L2 feed again. Frag-major G: linear
// LDS writes (embed) and reads (AREAD) -> ~0 bank conflicts.
__global__ __launch_bounds__(512, 2)
void k_mlp(const float* __restrict__ pos, const float* __restrict__ feat,
           const int* __restrict__ nbr_idx, const void* __restrict__ mask_raw,
           const int* __restrict__ mask_fmt,
           const float* __restrict__ W_in, const float* __restrict__ b_in,
           const float* __restrict__ dstv,
           const unsigned short* __restrict__ W1sf,
           unsigned short* __restrict__ aggpre, float* __restrict__ cntf)
{
    __shared__ unsigned short G[8*12*64*8];   // 98304 B frag-major embeds
    __shared__ ushort4 WINTB[HIDDEN];         // 3072 B bf16 {w0,w1,w2,b}
    __shared__ float PF[128][7];              // 3584 B pos3,feat3,mval
    __shared__ float CNT[4];

    const int t  = threadIdx.x;
    const int bm = blockIdx.x;                // edges bm*128..; supers bm*4..
    const int l = t & 63, w = t >> 6;
    const int mg = w >> 2, ng = w & 3;
    const int lg = l >> 4, l15 = l & 15;

    // early: dstv slices (b1 already folded in) for this wave's 2 supernodes
    float dvreg[2][6];
    #pragma unroll
    for (int sl = 0; sl < 2; ++sl)
        #pragma unroll
        for (int nt = 0; nt < 6; ++nt)
            dvreg[sl][nt] = dstv[(size_t)(bm*4 + mg*2 + sl)*HIDDEN + ng*96 + nt*16 + l15];

    if (t < 128) {
        const int e  = bm*128 + t;
        const int pi = nbr_idx[e];
        PF[t][0]=pos[pi*3];  PF[t][1]=pos[pi*3+1];  PF[t][2]=pos[pi*3+2];
        PF[t][3]=feat[pi*3]; PF[t][4]=feat[pi*3+1]; PF[t][5]=feat[pi*3+2];
        const int fmt = *mask_fmt;
        const int mv  = fmt ? (int)((const unsigned char*)mask_raw)[e]
                            : ((const int*)mask_raw)[e];
        PF[t][6] = mv ? 1.0f : 0.0f;
    }
    if (t >= 128 && t < 128 + HIDDEN) {
        const int d = t - 128;
        ushort4 wv;
        wv.x = f2bf(W_in[d]); wv.y = f2bf(W_in[HIDDEN+d]);
        wv.z = f2bf(W_in[2*HIDDEN+d]); wv.w = f2bf(b_in[d]);
        WINTB[d] = wv;
    }
    __syncthreads();
    if (t < 4) {
        float c = 0.f;
        for (int s = 0; s < 32; ++s) c += PF[t*32+s][6];
        CNT[t] = c;   // ordered by the post-embed barrier
    }

    // ---- embed 128 rows x 384 dims into frag-major G ----
    // thread (er = t>>2, seg = t&3): row er, dims kt*32 + seg*8 .. +8
    // slot = (er>>4)*12*64 + kt*64 + seg*16 + (er&15)  (mtile = er>>4)
    {
        const int er = t >> 2, seg = t & 3;
        float frA[8], frB[8];
        #pragma unroll
        for (int i = 0; i < 8; ++i) {
            frA[i] = exp2f(-(float)(seg*8 + i)      * 0.2076205059304601f);
            frB[i] = exp2f(-(float)(32 + seg*8 + i) * 0.2076205059304601f);
        }
        const float f0 = PF[er][3], f1 = PF[er][4], f2 = PF[er][5];
        const float pc0 = PF[er][0], pc1 = PF[er][1], pc2 = PF[er][2];
        const int slotbase = (er>>4)*12*64 + seg*16 + (er&15);
        #pragma unroll
        for (int kt = 0; kt < 12; ++kt) {
            const float pc = (kt>>2)==0 ? pc0 : ((kt>>2)==1 ? pc1 : pc2);
            float v[8];
            #pragma unroll
            for (int i = 0; i < 8; ++i) {
                const float fr = (kt&1) ? frB[i] : frA[i];
                const float aa = pc * fr;
                const float base = ((kt>>1)&1) ? __cosf(aa) : __sinf(aa);
                const ushort4 wv = WINTB[kt*32 + seg*8 + i];
                v[i] = fmaf(__uint_as_float((unsigned)wv.x<<16), f0,
                       fmaf(__uint_as_float((unsigned)wv.y<<16), f1,
                       fmaf(__uint_as_float((unsigned)wv.z<<16), f2,
                            base + __uint_as_float((unsigned)wv.w<<16))));
            }
            *(bf16x8*)&G[(size_t)(slotbase + kt*64)*8] = pack8(v);
        }
    }
    __syncthreads();

    // ---- src GEMM: 4 mtiles (mg half) x 6 ntiles (ng quarter), K=384 ----
    f32x4 acc[4][6];
    #pragma unroll
    for (int mt=0; mt<4; ++mt)
        #pragma unroll
        for (int nt=0; nt<6; ++nt) acc[mt][nt] = (f32x4){0.f,0.f,0.f,0.f};

    bf16x8 bA[6], bB[6];
    #define LOADB(dst, kt)                                                      \
        { const unsigned short* bp_ = &W1sf[((size_t)((kt)*24 + ng*6)*64 + l)*8];\
          _Pragma("unroll")                                                     \
          for (int nt_ = 0; nt_ < 6; ++nt_)                                     \
              dst[nt_] = *(const bf16x8*)(bp_ + (size_t)nt_*512); }
    #define AREAD(a_, kt)                                                       \
        { _Pragma("unroll")                                                     \
          for (int mt_ = 0; mt_ < 4; ++mt_)                                     \
              a_[mt_] = *(const bf16x8*)&G[(size_t)((((mg*4 + mt_)*12 + (kt))*64) + l)*8]; }
    #define MFMA6(bfr, a_)                                                      \
        { __builtin_amdgcn_s_setprio(1);                                        \
          _Pragma("unroll")                                                     \
          for (int mt_ = 0; mt_ < 4; ++mt_)                                     \
              _Pragma("unroll")                                                 \
              for (int nt_ = 0; nt_ < 6; ++nt_)                                 \
                  acc[mt_][nt_] = __builtin_amdgcn_mfma_f32_16x16x32_bf16(      \
                      a_[mt_], bfr[nt_], acc[mt_][nt_], 0, 0, 0);               \
          __builtin_amdgcn_s_setprio(0); }

    LOADB(bA, 0); LOADB(bB, 1);
    #pragma unroll
    for (int kt = 0; kt < 12; kt += 2) {
        bf16x8 a[4];
        AREAD(a, kt);
        MFMA6(bA, a);
        if (kt + 2 < 12) LOADB(bA, kt + 2);
        AREAD(a, kt + 1);
        MFMA6(bB, a);
        if (kt + 3 < 12) LOADB(bB, kt + 3);
    }

    // ---- +dstv, gelu, masked mean -> aggpre (bf16) ----
    float mvr[4][4];
    #pragma unroll
    for (int mt=0; mt<4; ++mt)
        #pragma unroll
        for (int r=0; r<4; ++r)
            mvr[mt][r] = PF[(mg*4 + mt)*16 + lg*4 + r][6];
    #pragma unroll
    for (int nt=0; nt<6; ++nt) {
        const int col = ng*96 + nt*16 + l15;
        float s0 = 0.f, s1 = 0.f;
        #pragma unroll
        for (int mt=0; mt<4; ++mt) {
            const float dv = dvreg[mt>>1][nt];
            float p = 0.f;
            #pragma unroll
            for (int r=0; r<4; ++r)
                p += mvr[mt][r] * gelu(acc[mt][nt][r] + dv);
            if (mt < 2) s0 += p; else s1 += p;
        }
        s0 += __shfl_xor(s0,16); s0 += __shfl_xor(s0,32);
        s1 += __shfl_xor(s1,16); s1 += __shfl_xor(s1,32);
        if (lg == 0) {
            const int sn0 = bm*4 + mg*2;
            aggpre[(size_t)sn0*HIDDEN + col]     = f2bf(s0 / fmaxf(CNT[mg*2],1.f));
            aggpre[(size_t)(sn0+1)*HIDDEN + col] = f2bf(s1 / fmaxf(CNT[mg*2+1],1.f));
        }
    }
    if (t < 4) cntf[bm*4 + t] = CNT[t];
    #undef LOADB
    #undef AREAD
    #undef MFMA6
}

// ---- K4: aggb = aggpre @ W2 + b2*(cnt>0). 128 blocks = 32 rg x 4 cq ----
__global__ __launch_bounds__(256)
void k_agg(const unsigned short* __restrict__ aggpre,
           const unsigned short* __restrict__ w2f,
           const float* __restrict__ b2, const float* __restrict__ cntf,
           unsigned short* __restrict__ aggb) {
    const int rg = blockIdx.x >> 2, cq = blockIdx.x & 3;
    const int t = threadIdx.x, w = t>>6, l = t&63, lg = l>>4, l15 = l&15;
    const int wgm = w>>1, wgn = w&1;
    const int r0 = rg*64 + wgm*32;
    const int ntb = cq*6 + wgn*3;
    f32x4 acc[2][3];
    #pragma unroll
    for (int mt=0; mt<2; ++mt)
        #pragma unroll
        for (int nt=0; nt<3; ++nt) acc[mt][nt] = (f32x4){0.f,0.f,0.f,0.f};
    #pragma unroll 2
    for (int kt = 0; kt < 12; ++kt) {
        bf16x8 a[2], bfr[3];
        const unsigned short* bpp = &w2f[((size_t)(kt*24 + ntb)*64 + l)*8];
        #pragma unroll
        for (int nt=0; nt<3; ++nt) bfr[nt] = *(const bf16x8*)(bpp + (size_t)nt*512);
        #pragma unroll
        for (int mt=0; mt<2; ++mt)
            a[mt] = *(const bf16x8*)&aggpre[(size_t)(r0 + mt*16 + l15)*HIDDEN + kt*32 + lg*8];
        #pragma unroll
        for (int mt=0; mt<2; ++mt)
            #pragma unroll
            for (int nt=0; nt<3; ++nt)
                acc[mt][nt] = __builtin_amdgcn_mfma_f32_16x16x32_bf16(a[mt], bfr[nt], acc[mt][nt], 0,0,0);
    }
    #pragma unroll
    for (int mt=0; mt<2; ++mt)
        #pragma unroll
        for (int nt=0; nt<3; ++nt) {
            const int col = cq*96 + wgn*48 + nt*16 + l15;
            const float bb = b2[col];
            #pragma unroll
            for (int r=0; r<4; ++r) {
                const int row = r0 + mt*16 + lg*4 + r;
                const float nz = (cntf[row] > 0.f) ? 1.f : 0.f;
                aggb[(size_t)row*HIDDEN + col] = f2bf(acc[mt][nt][r] + bb*nz);
            }
        }
}

// ---- K5: projection out = [aggb|snxb] @ Wp + bp. 128 blocks = 32 rg x 4 cq ----
__global__ __launch_bounds__(256)
void k_proj(const unsigned short* __restrict__ aggb,
            const unsigned short* __restrict__ snxb,
            const unsigned short* __restrict__ wpf,
            const float* __restrict__ bp, float* __restrict__ out) {
    const int rg = blockIdx.x >> 2, cq = blockIdx.x & 3;
    const int t = threadIdx.x, w = t>>6, l = t&63, lg = l>>4, l15 = l&15;
    const int wgm = w>>1, wgn = w&1;
    const int r0 = rg*64 + wgm*32;
    const int ntb = cq*6 + wgn*3;
    f32x4 acc[2][3];
    #pragma unroll
    for (int mt=0; mt<2; ++mt)
        #pragma unroll
        for (int nt=0; nt<3; ++nt) acc[mt][nt] = (f32x4){0.f,0.f,0.f,0.f};
    #pragma unroll 2
    for (int kt = 0; kt < 24; ++kt) {
        const unsigned short* Ab = (kt < 12) ? aggb : snxb;
        const unsigned short* Wb = (kt < 12) ? wpf  : wpf + WBLK;
        const int ktt = (kt < 12) ? kt : kt - 12;
        bf16x8 a[2], bfr[3];
        const unsigned short* bpp = &Wb[((size_t)(ktt*24 + ntb)*64 + l)*8];
        #pragma unroll
        for (int nt=0; nt<3; ++nt) bfr[nt] = *(const bf16x8*)(bpp + (size_t)nt*512);
        #pragma unroll
        for (int mt=0; mt<2; ++mt)
            a[mt] = *(const bf16x8*)&Ab[(size_t)(r0 + mt*16 + l15)*HIDDEN + ktt*32 + lg*8];
        #pragma unroll
        for (int mt=0; mt<2; ++mt)
            #pragma unroll
            for (int nt=0; nt<3; ++nt)
                acc[mt][nt] = __builtin_amdgcn_mfma_f32_16x16x32_bf16(a[mt], bfr[nt], acc[mt][nt], 0,0,0);
    }
    #pragma unroll
    for (int mt=0; mt<2; ++mt)
        #pragma unroll
        for (int nt=0; nt<3; ++nt) {
            const int col = cq*96 + wgn*48 + nt*16 + l15;
            #pragma unroll
            for (int r=0; r<4; ++r) {
                const int row = r0 + mt*16 + lg*4 + r;
                out[(size_t)row*HIDDEN + col] = acc[mt][nt][r] + bp[col];
            }
        }
}

extern "C" void kernel_launch(void* const* d_in, const int* in_sizes, int n_in,
                              void* d_out, int out_size, void* d_ws, size_t ws_size,
                              hipStream_t stream) {
    const float* pos   = (const float*)d_in[0];
    const float* feat  = (const float*)d_in[1];
    const int*   sn    = (const int*)d_in[2];
    const int*   nbr   = (const int*)d_in[3];
    const void*  mask  = d_in[4];
    const float* W_in  = (const float*)d_in[5];
    const float* b_in  = (const float*)d_in[6];
    const float* W1    = (const float*)d_in[7];
    const float* b1    = (const float*)d_in[8];
    const float* W2    = (const float*)d_in[9];
    const float* b2    = (const float*)d_in[10];
    const float* Wp    = (const float*)d_in[11];
    const float* bpv   = (const float*)d_in[12];
    float* out = (float*)d_out;

    char* base = (char*)d_ws;
    int* flag = (int*)base;
    unsigned short* w1sf = (unsigned short*)(base + 256);
    unsigned short* w1df = w1sf + WBLK;
    unsigned short* w2f  = w1df + WBLK;
    unsigned short* wpf  = w2f  + WBLK;                  // 2 blocks (768 rows)
    unsigned short* snxb = wpf  + 2*(size_t)WBLK;        // 2048*384 bf16
    unsigned short* aggb = snxb + (size_t)NSUPER*HIDDEN;
    unsigned short* aggp = aggb + (size_t)NSUPER*HIDDEN; // 2048*384 bf16
    float* cntf = (float*)(aggp + (size_t)NSUPER*HIDDEN); // 2048 f32
    float* dstv = cntf + NSUPER;                          // 2048*384 f32

    hipLaunchKernelGGL(prep, dim3(393), dim3(256), 0, stream,
                       W1, W2, Wp, (const unsigned int*)mask,
                       pos, feat, sn, W_in, b_in,
                       w1sf, w1df, w2f, wpf, snxb, flag);
    hipLaunchKernelGGL(k_dstv, dim3(128), dim3(256), 0, stream,
                       snxb, w1df, b1, dstv);
    hipLaunchKernelGGL(k_mlp, dim3(512), dim3(512), 0, stream,
                       pos, feat, nbr, mask, flag, W_in, b_in, dstv,
                       w1sf, aggp, cntf);
    hipLaunchKernelGGL(k_agg, dim3(128), dim3(256), 0, stream,
                       aggp, w2f, b2, cntf, aggb);
    hipLaunchKernelGGL(k_proj, dim3(128), dim3(256), 0, stream,
                       aggb, snxb, wpf, bpv, out);
}